// Round 1
// baseline (1083.221 us; speedup 1.0000x reference)
//
#include <hip/hip_runtime.h>

#define EPS 1e-6f

// DPP helper: v += v rotated by CTRL within each 16-lane row (row_ror:n = 0x120+n)
template <int CTRL>
__device__ __forceinline__ float dpp_add(float v) {
  int moved = __builtin_amdgcn_update_dpp(0, __float_as_int(v), CTRL, 0xF, 0xF, false);
  return v + __int_as_float(moved);
}

// ---------------------------------------------------------------------------
// Kernel A: P[b,n,r] = sum_d x[b,n,d] * bases[b,d,r]
// grid 256 = 16 batches x 16 row-groups (32 rows/WG); block 256 (4 waves x 8 rows)
// Also zeros CtC (blocks 0..15) and optionally writes coef = softmax(100*P).
// ---------------------------------------------------------------------------
__global__ __launch_bounds__(256) void kernelA(
    const float* __restrict__ x, const float* __restrict__ bases,
    float* __restrict__ P, float* __restrict__ coef,
    float* __restrict__ CtC, int do_softmax)
{
  __shared__ __align__(16) float lb[512 * 20];  // bases chunk [dl][r], stride 20 (40 KB)
  const int tid = threadIdx.x;
  if (blockIdx.x < 16) CtC[blockIdx.x * 256 + tid] = 0.0f;  // 16*256 = 4096 floats
  const int b = blockIdx.x >> 4;
  const int grp = blockIdx.x & 15;
  const int w = tid >> 6;
  const int lane = tid & 63;
  const int n0 = grp * 32 + w * 8;
  const float* __restrict__ xp = x + ((size_t)(b * 512 + n0)) * 4096;
  const float* __restrict__ bp = bases + ((size_t)b) * 4096 * 16;

  float acc[8][16];
#pragma unroll
  for (int i = 0; i < 8; ++i)
#pragma unroll
    for (int r = 0; r < 16; ++r) acc[i][r] = 0.0f;

  for (int c = 0; c < 8; ++c) {
    const int d0 = c * 512;
    // stage bases[d0:d0+512, 0:16] into LDS (row-major, stride 20 words)
    const float4* __restrict__ src = (const float4*)(bp + (size_t)d0 * 16);
#pragma unroll
    for (int k = 0; k < 8; ++k) {
      int idx = k * 256 + tid;          // 2048 float4 = 512 rows x 4 quads
      int dl = idx >> 2, q = idx & 3;
      *(float4*)(&lb[dl * 20 + q * 4]) = src[idx];
    }
    __syncthreads();
#pragma unroll
    for (int j = 0; j < 8; ++j) {
      const int dl = j * 64 + lane;
      float xv[8];
#pragma unroll
      for (int i = 0; i < 8; ++i) xv[i] = xp[(size_t)i * 4096 + d0 + dl];
      const float* row = &lb[dl * 20];
#pragma unroll
      for (int q = 0; q < 4; ++q) {
        float4 bv = *(const float4*)(row + q * 4);  // b128, ~2-way conflicts (free)
#pragma unroll
        for (int i = 0; i < 8; ++i) {
          acc[i][q * 4 + 0] = fmaf(xv[i], bv.x, acc[i][q * 4 + 0]);
          acc[i][q * 4 + 1] = fmaf(xv[i], bv.y, acc[i][q * 4 + 1]);
          acc[i][q * 4 + 2] = fmaf(xv[i], bv.z, acc[i][q * 4 + 2]);
          acc[i][q * 4 + 3] = fmaf(xv[i], bv.w, acc[i][q * 4 + 3]);
        }
      }
    }
    __syncthreads();
  }

  // reduce each acc[i][r] across the 64 lanes: 4 DPP row_ror levels + 2 shfl levels
#pragma unroll
  for (int i = 0; i < 8; ++i)
#pragma unroll
    for (int r = 0; r < 16; ++r) {
      float v = acc[i][r];
      v = dpp_add<0x121>(v);  // ror 1
      v = dpp_add<0x122>(v);  // ror 2
      v = dpp_add<0x124>(v);  // ror 4
      v = dpp_add<0x128>(v);  // ror 8  -> row(16)-sum in every lane
      v += __shfl_xor(v, 16, 64);
      v += __shfl_xor(v, 32, 64);
      acc[i][r] = v;
    }

  if (lane == 0) {
    float* __restrict__ prow = P + ((size_t)(b * 512 + n0)) * 16;
#pragma unroll
    for (int i = 0; i < 8; ++i)
#pragma unroll
      for (int r = 0; r < 16; ++r) prow[i * 16 + r] = acc[i][r];
    if (do_softmax) {
      float* __restrict__ crow = coef + ((size_t)(b * 512 + n0)) * 16;
#pragma unroll
      for (int i = 0; i < 8; ++i) {
        float m = acc[i][0];
#pragma unroll
        for (int r = 1; r < 16; ++r) m = fmaxf(m, acc[i][r]);
        float e[16];
        float s = 0.0f;
#pragma unroll
        for (int r = 0; r < 16; ++r) { e[r] = __expf(100.0f * (acc[i][r] - m)); s += e[r]; }
        float inv = 1.0f / s;
#pragma unroll
        for (int r = 0; r < 16; ++r) crow[i * 16 + r] = e[r] * inv;
      }
    }
  }
}

// ---------------------------------------------------------------------------
// Gram kernel: out[b, s*16+r] += sum_l M[b, sl*256+l, r] * M[b, sl*256+l, s]
// grid (L/256, 16); block 256. atomicAdd into pre-zeroed out.
// ---------------------------------------------------------------------------
__global__ __launch_bounds__(256) void kernelGram(
    const float* __restrict__ M, float* __restrict__ out, int L)
{
  __shared__ __align__(16) float sm[256 * 20];
  __shared__ __align__(16) float part[4 * 272];
  const int tid = threadIdx.x;
  const int b = blockIdx.y;
  const int sl = blockIdx.x;
  const float4* __restrict__ src = (const float4*)(M + ((size_t)b * L + (size_t)sl * 256) * 16);
#pragma unroll
  for (int k = 0; k < 4; ++k) {
    int idx = k * 256 + tid;            // 1024 float4 = 256 rows x 4 quads
    int row = idx >> 2, q = idx & 3;
    *(float4*)(&sm[row * 20 + q * 4]) = src[idx];
  }
  __syncthreads();
  const int rq = tid & 3;
  const int s = (tid >> 2) & 15;
  const int g = tid >> 6;               // 4 l-groups of 64 rows
  float a0 = 0.f, a1 = 0.f, a2 = 0.f, a3 = 0.f;
#pragma unroll 4
  for (int l = g * 64; l < g * 64 + 64; ++l) {
    float4 bv = *(const float4*)(&sm[l * 20 + rq * 4]);
    float cs = sm[l * 20 + s];
    a0 = fmaf(cs, bv.x, a0);
    a1 = fmaf(cs, bv.y, a1);
    a2 = fmaf(cs, bv.z, a2);
    a3 = fmaf(cs, bv.w, a3);
  }
  *(float4*)(&part[g * 272 + s * 16 + rq * 4]) = make_float4(a0, a1, a2, a3);
  __syncthreads();
  float v = part[0 * 272 + tid] + part[1 * 272 + tid] + part[2 * 272 + tid] + part[3 * 272 + tid];
  atomicAdd(out + b * 256 + tid, v);
}

// ---------------------------------------------------------------------------
// Coef update: coef[b,n,r] *= P[b,n,r] / (sum_s coef[b,n,s]*BtB[b,s,r] + eps)
// grid 32 (2 blocks/batch); block 256 (thread = one n row). Also zeros BtBz.
// ---------------------------------------------------------------------------
__global__ __launch_bounds__(256) void kernelCU(
    float* __restrict__ coef, const float* __restrict__ P,
    const float* __restrict__ BtBr, float* __restrict__ BtBz)
{
  const int tid = threadIdx.x;
  BtBz[blockIdx.x * 128 + (tid & 127)] = 0.0f;  // 32*128 = 4096 (each written twice, fine)
  const int b = blockIdx.x >> 1;
  const int n = ((blockIdx.x & 1) << 8) + tid;
  float* __restrict__ crow = coef + ((size_t)(b * 512 + n)) * 16;
  const float* __restrict__ prow = P + ((size_t)(b * 512 + n)) * 16;
  const float* __restrict__ btb = BtBr + b * 256;
  float cv[16], den[16];
#pragma unroll
  for (int r = 0; r < 16; ++r) cv[r] = crow[r];
#pragma unroll
  for (int r = 0; r < 16; ++r) den[r] = 0.f;
#pragma unroll
  for (int s2 = 0; s2 < 16; ++s2) {
    const float bs = cv[s2];
#pragma unroll
    for (int r = 0; r < 16; ++r) den[r] = fmaf(bs, btb[s2 * 16 + r], den[r]);
  }
#pragma unroll
  for (int r = 0; r < 16; ++r) crow[r] = cv[r] * prow[r] / (den[r] + EPS);
}

// ---------------------------------------------------------------------------
// Kernel B: Q[b,d,r] = sum_n x[b,n,d]*coef[b,n,r]; then in-place
// bases[b,d,r] *= Q / (sum_s bases[b,d,s]*CtC[b,s,r] + eps)
// grid (16 d-tiles, 16 b); block 256 (thread = one d).
// ---------------------------------------------------------------------------
__global__ __launch_bounds__(256) void kernelB(
    const float* __restrict__ x, const float* __restrict__ coef,
    float* __restrict__ bases, const float* __restrict__ CtC)
{
  const int tid = threadIdx.x;
  const int b = blockIdx.y;
  const int d = blockIdx.x * 256 + tid;
  const float* __restrict__ xp = x + ((size_t)b * 512) * 4096 + d;
  const float* __restrict__ cp = coef + (size_t)b * 512 * 16;
  float acc[16];
#pragma unroll
  for (int r = 0; r < 16; ++r) acc[r] = 0.f;
#pragma unroll 4
  for (int n = 0; n < 512; ++n) {
    const float xv = xp[(size_t)n * 4096];              // coalesced b32
    const float* __restrict__ crow = cp + n * 16;       // wave-uniform -> s_load
#pragma unroll
    for (int r = 0; r < 16; ++r) acc[r] = fmaf(xv, crow[r], acc[r]);
  }
  float* __restrict__ brow = bases + ((size_t)b * 4096 + d) * 16;
  float bv[16];
#pragma unroll
  for (int r = 0; r < 16; ++r) bv[r] = brow[r];
  const float* __restrict__ ctc = CtC + b * 256;
  float den[16];
#pragma unroll
  for (int r = 0; r < 16; ++r) den[r] = 0.f;
#pragma unroll
  for (int s2 = 0; s2 < 16; ++s2) {
    const float bs = bv[s2];
#pragma unroll
    for (int r = 0; r < 16; ++r) den[r] = fmaf(bs, ctc[s2 * 16 + r], den[r]);
  }
#pragma unroll
  for (int r = 0; r < 16; ++r) brow[r] = bv[r] * acc[r] / (den[r] + EPS);
}

// ---------------------------------------------------------------------------
// Output: out[b,n,d] = sum_r bases[b,d,r]*coef[b,n,r]
// grid (16 d-tiles, 16 b); block 256 (thread = one d). Coalesced stores.
// ---------------------------------------------------------------------------
__global__ __launch_bounds__(256) void kernelOut(
    const float* __restrict__ bases, const float* __restrict__ coef,
    float* __restrict__ out)
{
  const int tid = threadIdx.x;
  const int b = blockIdx.y;
  const int d = blockIdx.x * 256 + tid;
  const float* __restrict__ brow = bases + ((size_t)b * 4096 + d) * 16;
  float bv[16];
#pragma unroll
  for (int r = 0; r < 16; ++r) bv[r] = brow[r];
  const float* __restrict__ cp = coef + (size_t)b * 512 * 16;
  float* __restrict__ op = out + ((size_t)b * 512) * 4096 + d;
#pragma unroll 4
  for (int n = 0; n < 512; ++n) {
    const float* __restrict__ crow = cp + n * 16;       // wave-uniform
    float v = 0.f;
#pragma unroll
    for (int r = 0; r < 16; ++r) v = fmaf(bv[r], crow[r], v);
    op[(size_t)n * 4096] = v;
  }
}

// ---------------------------------------------------------------------------
extern "C" void kernel_launch(void* const* d_in, const int* in_sizes, int n_in,
                              void* d_out, int out_size, void* d_ws, size_t ws_size,
                              hipStream_t stream) {
  const float* x = (const float*)d_in[0];         // 16*512*4096
  const float* bases_in = (const float*)d_in[1];  // 16*4096*16
  float* out = (float*)d_out;                     // 16*512*4096
  float* ws = (float*)d_ws;

  float* bases = ws;               // 1,048,576 floats (4 MB), working copy
  float* coef  = bases + 1048576;  // 131,072
  float* P     = coef + 131072;    // 131,072
  float* btb0  = P + 131072;       // 4,096
  float* btb1  = btb0 + 4096;      // 4,096
  float* ctc   = btb1 + 4096;      // 4,096
  float* btb[2] = {btb0, btb1};

  hipMemsetAsync(btb0, 0, 4096 * sizeof(float), stream);
  hipMemcpyAsync(bases, bases_in, 1048576 * sizeof(float),
                 hipMemcpyDeviceToDevice, stream);

  // init: P0 = X^T B0, coef = softmax(100*P0); CtC zeroed inside A; BtB0 = gram(B0)
  kernelA<<<256, 256, 0, stream>>>(x, bases, P, coef, ctc, 1);
  kernelGram<<<dim3(16, 16), 256, 0, stream>>>(bases, btb0, 4096);

  for (int t = 0; t < 7; ++t) {
    if (t > 0) kernelA<<<256, 256, 0, stream>>>(x, bases, P, coef, ctc, 0);
    // coef update reads BtB[t&1], zeros BtB[(t+1)&1] for this iter's gramB
    kernelCU<<<32, 256, 0, stream>>>(coef, P, btb[t & 1], btb[(t + 1) & 1]);
    kernelGram<<<dim3(2, 16), 256, 0, stream>>>(coef, ctc, 512);     // CtC(new coef)
    kernelB<<<dim3(16, 16), 256, 0, stream>>>(x, coef, bases, ctc);  // bases update
    kernelGram<<<dim3(16, 16), 256, 0, stream>>>(bases, btb[(t + 1) & 1], 4096);
  }

  // final compute_coef with bases_7 / BtB[1], then reconstruct
  kernelA<<<256, 256, 0, stream>>>(x, bases, P, coef, ctc, 0);
  kernelCU<<<32, 256, 0, stream>>>(coef, P, btb[1], btb[0]);
  kernelOut<<<dim3(16, 16), 256, 0, stream>>>(bases, coef, out);
}